// Round 4
// baseline (3049.312 us; speedup 1.0000x reference)
//
#include <hip/hip_runtime.h>
#include <hip/hip_bf16.h>

typedef unsigned short u16;
typedef __bf16 bf16x8 __attribute__((ext_vector_type(8)));
typedef float floatx4 __attribute__((ext_vector_type(4)));
typedef unsigned uintx4 __attribute__((ext_vector_type(4)));
typedef unsigned short ushortx4 __attribute__((ext_vector_type(4)));

static constexpr int D = 128;

__device__ inline float bflo(unsigned u) { return __uint_as_float(u << 16); }
__device__ inline float bfhi(unsigned u) { return __uint_as_float(u & 0xffff0000u); }
__device__ inline float bf2f(u16 v) { return __uint_as_float((unsigned)v << 16); }
__device__ inline unsigned packbf(float a, float b) {
    unsigned lo = __hip_bfloat16_raw(__float2bfloat16(a)).x;
    unsigned hi = __hip_bfloat16_raw(__float2bfloat16(b)).x;
    return lo | (hi << 16);
}

// ---------------- zero ints ----------------
__global__ void zero_int_kernel(int* __restrict__ p, int n) {
    int i = blockIdx.x * blockDim.x + threadIdx.x;
    int stride = gridDim.x * blockDim.x;
    for (; i < n; i += stride) p[i] = 0;
}

// ---------------- convert x fp32 -> bf16 ----------------
__global__ void convert_x_kernel(const float* __restrict__ x, u16* __restrict__ xb, int n4) {
    int i = blockIdx.x * blockDim.x + threadIdx.x;
    int stride = gridDim.x * blockDim.x;
    for (; i < n4; i += stride) {
        floatx4 v = __builtin_nontemporal_load((const floatx4*)x + i);
        ushortx4 o;
        o.x = __hip_bfloat16_raw(__float2bfloat16(v.x)).x;
        o.y = __hip_bfloat16_raw(__float2bfloat16(v.y)).x;
        o.z = __hip_bfloat16_raw(__float2bfloat16(v.z)).x;
        o.w = __hip_bfloat16_raw(__float2bfloat16(v.w)).x;
        *((ushortx4*)xb + i) = o;
    }
}

// ---------------- per-dst counts: all three edge types in one launch ----------------
__global__ void count3_kernel(const int* __restrict__ dst0, const int* __restrict__ dst1,
                              const int* __restrict__ dst2, int* __restrict__ counts,
                              int E, int N) {
    int i = blockIdx.x * blockDim.x + threadIdx.x;
    if (i < E) {
        atomicAdd(&counts[dst0[i]], 1);
    } else if (i < 2 * E) {
        atomicAdd(&counts[N + dst1[i - E]], 1);
    } else if (i < 3 * E) {
        atomicAdd(&counts[2 * N + dst2[i - 2 * E]], 1);
    }
}

// ---------------- offsets: wave scan + one atomic per wave ----------------
// Each wave covers an ALIGNED group of 64 consecutive nodes, so every 64-node
// run is contiguous+ascending in csr space (the fused kernel relies on this).
__global__ __launch_bounds__(256) void offs_kernel(const int* __restrict__ counts,
                                                   int* __restrict__ offs,
                                                   int* __restrict__ cursor,
                                                   int* __restrict__ counters,
                                                   int N, int bpt) {
    int type = blockIdx.x / bpt;
    int n = (blockIdx.x - type * bpt) * 256 + threadIdx.x;
    int lane = threadIdx.x & 63;
    int i = type * N + n;
    int v = (n < N) ? counts[i] : 0;
    int incl = v;
#pragma unroll
    for (int d = 1; d < 64; d <<= 1) {
        int t = __shfl_up(incl, d, 64);
        if (lane >= d) incl += t;
    }
    int total = __shfl(incl, 63, 64);
    int base = 0;
    if (lane == 63) base = atomicAdd(&counters[type], total);
    base = __shfl(base, 63, 64);
    int off = base + incl - v;
    if (n < N) {
        offs[i] = off;
        cursor[i] = off;
    }
}

// ---------------- CSR scatter (all three edge types, one launch) ----------------
// csr2 is PADDED to stride 4 so the triple store is one dwordx4.
__global__ void scatter3_kernel(const int* __restrict__ dst0, const int* __restrict__ src0,
                                const int* __restrict__ dst1, const int* __restrict__ src1,
                                const int* __restrict__ dst2, const int* __restrict__ src2,
                                int* __restrict__ cursor,
                                int* __restrict__ csr0, int* __restrict__ csr1,
                                int* __restrict__ csr2, int E, int N) {
    int i = blockIdx.x * blockDim.x + threadIdx.x;
    if (i < E) {
        int d = __builtin_nontemporal_load(dst0 + i);
        int pos = atomicAdd(&cursor[d], 1);
        csr0[pos] = __builtin_nontemporal_load(src0 + i);
    } else if (i < 2 * E) {
        int e = i - E;
        int d = __builtin_nontemporal_load(dst1 + e);
        int pos = atomicAdd(&cursor[N + d], 1);
        int2 s = *(const int2*)(src1 + e * 2);  // 8B aligned
        *(int2*)(csr1 + pos * 2) = s;
    } else if (i < 3 * E) {
        int e = i - 2 * E;
        int d = __builtin_nontemporal_load(dst2 + e);
        int pos = atomicAdd(&cursor[2 * N + d], 1);
        int a = __builtin_nontemporal_load(src2 + e * 3);
        int b = __builtin_nontemporal_load(src2 + e * 3 + 1);
        int c = __builtin_nontemporal_load(src2 + e * 3 + 2);
        int4 o; o.x = a; o.y = b; o.z = c; o.w = 0;
        *(int4*)(csr2 + pos * 4) = o;
    }
}

// ---------------- pack fp32 weights into bf16 MFMA B-fragment order ----------------
// Wp layout (u16): [0,16384)=WC^T, [16384,32768)=WA0, [32768,65536)=WA1, [65536,114688)=WA2
__global__ void pack_all_kernel(const float* __restrict__ WC, const float* __restrict__ WA0,
                                const float* __restrict__ WA1, const float* __restrict__ WA2,
                                u16* __restrict__ Wp) {
    int c = blockIdx.x * blockDim.x + threadIdx.x;  // 0 .. 14335 chunks
    if (c >= 14336) return;
    const float* W;
    int K, transposed, cl;
    u16* out;
    if (c < 2048) {
        W = WC; K = 128; transposed = 1; cl = c; out = Wp;
    } else if (c < 4096) {
        W = WA0; K = 128; transposed = 0; cl = c - 2048; out = Wp + 16384;
    } else if (c < 8192) {
        W = WA1; K = 256; transposed = 0; cl = c - 4096; out = Wp + 32768;
    } else {
        W = WA2; K = 384; transposed = 0; cl = c - 8192; out = Wp + 65536;
    }
    int s = cl >> 9, rem = cl & 511, t = rem >> 6, l = rem & 63;
    int kbase = 32 * s + ((l >> 4) * 8);
    int n = 16 * t + (l & 15);
#pragma unroll
    for (int j = 0; j < 8; ++j) {
        int k = kbase + j;
        float w = transposed ? W[n * K + k] : W[k * D + n];
        out[(size_t)cl * 8 + j] = __hip_bfloat16_raw(__float2bfloat16(w)).x;
    }
}

// ================= FUSED: aggregation built in-LDS inside the GEMM K-loop =================
// Block = 128 output rows, 256 threads, 14 ksteps of K=64.
// ks 0-1: A-subtile = xb rows. ks 2-13: A-subtile = per-node mean of gathered
// half-rows for (type,slot,half) mapped from ks, built edge-parallel into an
// fp32 LDS tile via ds_add_f32 atomics; node found by binary search over the
// block's LDS-resident CSR offsets (two contiguous 64-node runs).
// AG never touches global memory (removes the 150+150 MB round-trip).

__device__ inline void mfma_step(const u16* __restrict__ Wp, int ks, int wave, int lane,
                                 const u16 As[128][72], floatx4 acc[2][8]) {
#pragma unroll
    for (int sub = 0; sub < 2; ++sub) {
        bf16x8 bfrag[8];
#pragma unroll
        for (int t = 0; t < 8; ++t)
            bfrag[t] = *(const bf16x8*)(Wp + (size_t)ks * 8192 + ((sub * 8 + t) * 64 + lane) * 8);
#pragma unroll
        for (int strip = 0; strip < 2; ++strip) {
            int row = wave * 32 + strip * 16 + (lane & 15);
            bf16x8 afrag = *(const bf16x8*)(&As[row][sub * 32 + ((lane >> 4) * 8)]);
#pragma unroll
            for (int t = 0; t < 8; ++t)
                acc[strip][t] = __builtin_amdgcn_mfma_f32_16x16x32_bf16(
                    afrag, bfrag[t], acc[strip][t], 0, 0, 0);
        }
    }
}

__device__ inline void ks_map(int ks, int& t, int& St, int& s, int& half) {
    if (ks < 4)      { t = 0; St = 1; s = 0;             half = (ks - 2) & 1; }
    else if (ks < 8) { t = 1; St = 2; s = (ks - 4) >> 1; half = (ks - 4) & 1; }
    else             { t = 2; St = 4; s = (ks - 8) >> 1; half = (ks - 8) & 1; }
}

__device__ inline void gather_step(const u16* __restrict__ xb, const int* __restrict__ csrt,
                                   int St, int s, int half,
                                   const int* __restrict__ Lst_t,   // [128] starts
                                   const int* __restrict__ Lrs_t,   // [2] run starts
                                   const int* __restrict__ Lre_t,   // [2] run ends
                                   float* __restrict__ As32, int gidx, int li) {
#pragma unroll
    for (int r = 0; r < 2; ++r) {
        int re = Lre_t[r];
        const int* st = Lst_t + r * 64;
        for (int j = Lrs_t[r] + gidx; j < re; j += 16) {
            // largest i in [0,64) with st[i] <= j
            int lo = 0;
#pragma unroll
            for (int step = 32; step; step >>= 1) {
                int cand = lo + step;
                if (cand < 64 && st[cand] <= j) lo = cand;
            }
            int node = r * 64 + lo;
            int src = csrt[j * St + s];
            ushortx4 u = *(const ushortx4*)(xb + ((size_t)(unsigned)src << 7) + half * 64 + li * 4);
            float* dst = As32 + node * 64 + li * 4;
            (void)__hip_atomic_fetch_add(dst + 0, bf2f(u.x), __ATOMIC_RELAXED, __HIP_MEMORY_SCOPE_WORKGROUP);
            (void)__hip_atomic_fetch_add(dst + 1, bf2f(u.y), __ATOMIC_RELAXED, __HIP_MEMORY_SCOPE_WORKGROUP);
            (void)__hip_atomic_fetch_add(dst + 2, bf2f(u.z), __ATOMIC_RELAXED, __HIP_MEMORY_SCOPE_WORKGROUP);
            (void)__hip_atomic_fetch_add(dst + 3, bf2f(u.w), __ATOMIC_RELAXED, __HIP_MEMORY_SCOPE_WORKGROUP);
        }
    }
}

__global__ __launch_bounds__(256, 3) void fused_gemm_agg(
    const u16* __restrict__ xb, const int* __restrict__ counts, const int* __restrict__ offs,
    const int* __restrict__ csr0, const int* __restrict__ csr1, const int* __restrict__ csr2,
    const u16* __restrict__ Wp, const float* __restrict__ bC, float* __restrict__ out,
    int N) {
    __shared__ u16 As[128][72];          // 18.4 KB, 16B-aligned rows (144B stride)
    __shared__ float As32[128 * 64];     // 32 KB fp32 accumulation tile
    __shared__ int Lst[3][128];          // per-type csr segment starts (edge units)
    __shared__ int Lrs[3][2], Lre[3][2]; // per-type run start/end edge positions

    const int tid = threadIdx.x;
    const int wave = tid >> 6;
    const int lane = tid & 63;
    const int gidx = tid >> 4;  // 16 groups
    const int li = tid & 15;
    const int n0 = blockIdx.x * 128;

    // ---- init: CSR offsets + run bounds + zero As32 ----
    if (tid < 128) {
        int n = n0 + tid;
#pragma unroll
        for (int t = 0; t < 3; ++t)
            Lst[t][tid] = (n < N) ? offs[t * N + n] : 0x7fffffff;
    }
    if (tid < 6) {
        int t = tid >> 1, r = tid & 1;
        int nfirst = n0 + r * 64;
        int rs = 0, re = 0;
        if (nfirst < N) {
            int nlast = nfirst + 63;
            if (nlast > N - 1) nlast = N - 1;
            rs = offs[t * N + nfirst];
            re = offs[t * N + nlast] + counts[t * N + nlast];
        }
        Lrs[t][r] = rs;
        Lre[t][r] = re;
    }
    {
        floatx4 z = {0.f, 0.f, 0.f, 0.f};
#pragma unroll
        for (int q = 0; q < 8; ++q) *(floatx4*)(&As32[tid * 4 + q * 1024]) = z;
    }

    floatx4 acc[2][8];
#pragma unroll
    for (int p = 0; p < 2; ++p)
#pragma unroll
        for (int t = 0; t < 8; ++t) acc[p][t] = floatx4{0.f, 0.f, 0.f, 0.f};

    // ---- stage x-part ks=0 ----
#pragma unroll
    for (int it = 0; it < 4; ++it) {
        int chunk = tid + it * 256;
        int row = chunk >> 3, part = chunk & 7;
        int g = (n0 + row < N) ? (n0 + row) : n0;
        *(uintx4*)(&As[row][part * 8]) = *(const uintx4*)(xb + (size_t)g * D + part * 8);
    }
    __syncthreads();
    mfma_step(Wp, 0, wave, lane, As, acc);
    __syncthreads();
    // ---- stage x-part ks=1 ----
#pragma unroll
    for (int it = 0; it < 4; ++it) {
        int chunk = tid + it * 256;
        int row = chunk >> 3, part = chunk & 7;
        int g = (n0 + row < N) ? (n0 + row) : n0;
        *(uintx4*)(&As[row][part * 8]) = *(const uintx4*)(xb + (size_t)g * D + 64 + part * 8);
    }
    __syncthreads();
    {  // gather for ks=2 overlaps MFMA(1)
        int t, St, s, half;
        ks_map(2, t, St, s, half);
        gather_step(xb, csr0, St, s, half, Lst[0], Lrs[0], Lre[0], As32, gidx, li);
        mfma_step(Wp, 1, wave, lane, As, acc);
    }
    __syncthreads();

    // ---- ks 2..13: aggregated part ----
    const int crow = tid >> 1;     // convert-phase row
    const int chalf = tid & 1;     // convert-phase 32-col half
    for (int ks = 2; ks < 14; ++ks) {
        int t, St, s, half;
        ks_map(ks, t, St, s, half);
        // phase: normalize+convert As32 -> As (bf16), re-zero As32
        {
            int gn = n0 + crow;
            int dg = (gn < N) ? counts[t * N + gn] : 0;
            float nm = (dg > 0) ? 1.0f / (float)dg : 0.0f;
            floatx4 z = {0.f, 0.f, 0.f, 0.f};
#pragma unroll
            for (int q = 0; q < 4; ++q) {
                float* bp = &As32[crow * 64 + chalf * 32 + q * 8];
                floatx4 a = *(floatx4*)bp;
                floatx4 b = *(floatx4*)(bp + 4);
                uintx4 o;
                o.x = packbf(a.x * nm, a.y * nm);
                o.y = packbf(a.z * nm, a.w * nm);
                o.z = packbf(b.x * nm, b.y * nm);
                o.w = packbf(b.z * nm, b.w * nm);
                *(uintx4*)(&As[crow][chalf * 32 + q * 8]) = o;
                *(floatx4*)bp = z;
                *(floatx4*)(bp + 4) = z;
            }
        }
        __syncthreads();
        // phase: gather(ks+1) overlapped with MFMA(ks)
        if (ks < 13) {
            int t2, St2, s2, half2;
            ks_map(ks + 1, t2, St2, s2, half2);
            const int* csrt = (t2 == 0) ? csr0 : (t2 == 1) ? csr1 : csr2;
            gather_step(xb, csrt, St2, s2, half2, Lst[t2], Lrs[t2], Lre[t2], As32, gidx, li);
        }
        mfma_step(Wp, ks, wave, lane, As, acc);
        __syncthreads();
    }

    // ---- epilogue ----
#pragma unroll
    for (int strip = 0; strip < 2; ++strip) {
#pragma unroll
        for (int r = 0; r < 4; ++r) {
            int row = wave * 32 + strip * 16 + (lane >> 4) * 4 + r;
            int gn = n0 + row;
            if (gn >= N) continue;
            size_t base = (size_t)gn * D;
#pragma unroll
            for (int t = 0; t < 8; ++t) {
                int col = 16 * t + (lane & 15);
                out[base + col] = acc[strip][t][r] + bC[col];
            }
        }
    }
}

extern "C" void kernel_launch(void* const* d_in, const int* in_sizes, int n_in,
                              void* d_out, int out_size, void* d_ws, size_t ws_size,
                              hipStream_t stream) {
    const float* x = (const float*)d_in[0];
    const int* src0 = (const int*)d_in[1];
    const int* dst0 = (const int*)d_in[2];
    const int* src1 = (const int*)d_in[3];
    const int* dst1 = (const int*)d_in[4];
    const int* src2 = (const int*)d_in[5];
    const int* dst2 = (const int*)d_in[6];
    const float* WA0 = (const float*)d_in[7];
    const float* WA1 = (const float*)d_in[8];
    const float* WA2 = (const float*)d_in[9];
    const float* WC = (const float*)d_in[10];
    const float* bC = (const float*)d_in[11];

    const int N = in_sizes[0] / D;  // 100000
    const int E = in_sizes[2];      // 500000

    auto align256 = [](size_t v) { return (v + 255) & ~(size_t)255; };
    char* ws = (char*)d_ws;
    size_t ofs = 0;
    u16* xb = (u16*)(ws + ofs);      ofs = align256(ofs + (size_t)N * D * sizeof(u16));
    int* counts = (int*)(ws + ofs);  ofs = align256(ofs + ((size_t)3 * N + 4) * sizeof(int));
    int* counters = counts + 3 * N;  // 3 ints, zeroed with counts
    int* offs = (int*)(ws + ofs);    ofs = align256(ofs + (size_t)3 * N * sizeof(int));
    int* cursor = (int*)(ws + ofs);  ofs = align256(ofs + (size_t)3 * N * sizeof(int));
    int* csr0 = (int*)(ws + ofs);    // E ints
    int* csr1 = csr0 + E;            // 2E ints
    int* csr2 = csr1 + 2 * E;        // 4E ints (stride-4 padded)
    ofs = align256(ofs + (size_t)7 * E * sizeof(int));
    u16* Wp = (u16*)(ws + ofs);      ofs = align256(ofs + (size_t)896 * D * sizeof(u16));

    // prep
    zero_int_kernel<<<512, 256, 0, stream>>>(counts, 3 * N + 4);
    convert_x_kernel<<<1024, 256, 0, stream>>>(x, xb, N * D / 4);

    int cb3 = (3 * E + 255) / 256;
    count3_kernel<<<cb3, 256, 0, stream>>>(dst0, dst1, dst2, counts, E, N);

    int bpt = (N + 255) / 256;
    offs_kernel<<<3 * bpt, 256, 0, stream>>>(counts, offs, cursor, counters, N, bpt);

    scatter3_kernel<<<cb3, 256, 0, stream>>>(dst0, src0, dst1, src1, dst2, src2,
                                             cursor, csr0, csr1, csr2, E, N);

    // B matrix: ks 0-1 = WC^T, 2-3 = WA0, 4-7 = WA1, 8-13 = WA2
    pack_all_kernel<<<(14336 + 255) / 256, 256, 0, stream>>>(WC, WA0, WA1, WA2, Wp);

    fused_gemm_agg<<<(N + 127) / 128, 256, 0, stream>>>(xb, counts, offs,
                                                        csr0, csr1, csr2, Wp, bC,
                                                        (float*)d_out, N);
}

// Round 5
// 509.087 us; speedup vs baseline: 5.9898x; 5.9898x over previous
//
#include <hip/hip_runtime.h>
#include <hip/hip_bf16.h>

typedef unsigned short u16;
typedef __bf16 bf16x8 __attribute__((ext_vector_type(8)));
typedef float floatx4 __attribute__((ext_vector_type(4)));
typedef unsigned uintx4 __attribute__((ext_vector_type(4)));
typedef unsigned short ushortx4 __attribute__((ext_vector_type(4)));

static constexpr int D = 128;

__device__ inline float bflo(unsigned u) { return __uint_as_float(u << 16); }
__device__ inline float bfhi(unsigned u) { return __uint_as_float(u & 0xffff0000u); }
__device__ inline unsigned packbf(float a, float b) {
    unsigned lo = __hip_bfloat16_raw(__float2bfloat16(a)).x;
    unsigned hi = __hip_bfloat16_raw(__float2bfloat16(b)).x;
    return lo | (hi << 16);
}

// ---------------- zero ints ----------------
__global__ void zero_int_kernel(int* __restrict__ p, int n) {
    int i = blockIdx.x * blockDim.x + threadIdx.x;
    int stride = gridDim.x * blockDim.x;
    for (; i < n; i += stride) p[i] = 0;
}

// ---------------- merged prep: convert x | count3 | pack weights ----------------
// Three independent jobs dispatched by block range (one launch instead of three).
static constexpr int CVB = 1024;  // convert blocks

__global__ void prep_kernel(const float* __restrict__ x, u16* __restrict__ xb, int n4,
                            const int* __restrict__ dst0, const int* __restrict__ dst1,
                            const int* __restrict__ dst2, int* __restrict__ counts,
                            int E, int N, int cb3,
                            const float* __restrict__ WC, const float* __restrict__ WA0,
                            const float* __restrict__ WA1, const float* __restrict__ WA2,
                            u16* __restrict__ Wp) {
    int b = blockIdx.x;
    if (b < CVB) {
        // ---- convert x fp32 -> bf16 (x read once -> NT load; xb stays cached) ----
        int i = b * blockDim.x + threadIdx.x;
        int stride = CVB * blockDim.x;
        for (; i < n4; i += stride) {
            floatx4 v = __builtin_nontemporal_load((const floatx4*)x + i);
            ushortx4 o;
            o.x = __hip_bfloat16_raw(__float2bfloat16(v.x)).x;
            o.y = __hip_bfloat16_raw(__float2bfloat16(v.y)).x;
            o.z = __hip_bfloat16_raw(__float2bfloat16(v.z)).x;
            o.w = __hip_bfloat16_raw(__float2bfloat16(v.w)).x;
            *((ushortx4*)xb + i) = o;
        }
    } else if (b < CVB + cb3) {
        // ---- per-dst counts ----
        int i = (b - CVB) * blockDim.x + threadIdx.x;
        if (i < E) {
            atomicAdd(&counts[dst0[i]], 1);
        } else if (i < 2 * E) {
            atomicAdd(&counts[N + dst1[i - E]], 1);
        } else if (i < 3 * E) {
            atomicAdd(&counts[2 * N + dst2[i - 2 * E]], 1);
        }
    } else {
        // ---- pack fp32 weights into bf16 MFMA B-fragment order ----
        // Wp (u16): [0,16384)=WC^T, [16384,32768)=WA0, [32768,65536)=WA1, [65536,114688)=WA2
        int c = (b - CVB - cb3) * blockDim.x + threadIdx.x;
        if (c >= 14336) return;
        const float* W;
        int K, transposed, cl;
        u16* out;
        if (c < 2048) {
            W = WC; K = 128; transposed = 1; cl = c; out = Wp;
        } else if (c < 4096) {
            W = WA0; K = 128; transposed = 0; cl = c - 2048; out = Wp + 16384;
        } else if (c < 8192) {
            W = WA1; K = 256; transposed = 0; cl = c - 4096; out = Wp + 32768;
        } else {
            W = WA2; K = 384; transposed = 0; cl = c - 8192; out = Wp + 65536;
        }
        int s = cl >> 9, rem = cl & 511, t = rem >> 6, l = rem & 63;
        int kbase = 32 * s + ((l >> 4) * 8);
        int n = 16 * t + (l & 15);
#pragma unroll
        for (int j = 0; j < 8; ++j) {
            int k = kbase + j;
            float w = transposed ? W[n * K + k] : W[k * D + n];
            out[(size_t)cl * 8 + j] = __hip_bfloat16_raw(__float2bfloat16(w)).x;
        }
    }
}

// ---------------- offsets: wave scan + one atomic per wave ----------------
// CSR segments need only be disjoint+contiguous per node, not sorted.
__global__ __launch_bounds__(256) void offs_kernel(const int* __restrict__ counts,
                                                   int* __restrict__ offs,
                                                   int* __restrict__ cursor,
                                                   int* __restrict__ counters,
                                                   int N, int bpt) {
    int type = blockIdx.x / bpt;
    int n = (blockIdx.x - type * bpt) * 256 + threadIdx.x;
    int lane = threadIdx.x & 63;
    int i = type * N + n;
    int v = (n < N) ? counts[i] : 0;
    int incl = v;
#pragma unroll
    for (int d = 1; d < 64; d <<= 1) {
        int t = __shfl_up(incl, d, 64);
        if (lane >= d) incl += t;
    }
    int total = __shfl(incl, 63, 64);
    int base = 0;
    if (lane == 63) base = atomicAdd(&counters[type], total);
    base = __shfl(base, 63, 64);
    int off = base + incl - v;
    if (n < N) {
        offs[i] = off;
        cursor[i] = off;
    }
}

// ---------------- CSR scatter (all three edge types, one launch) ----------------
// src/dst are last-use here -> NT loads. csr is re-read by aggregate -> NORMAL stores.
__global__ void scatter3_kernel(const int* __restrict__ dst0, const int* __restrict__ src0,
                                const int* __restrict__ dst1, const int* __restrict__ src1,
                                const int* __restrict__ dst2, const int* __restrict__ src2,
                                int* __restrict__ cursor,
                                int* __restrict__ csr0, int* __restrict__ csr1,
                                int* __restrict__ csr2, int E, int N) {
    int i = blockIdx.x * blockDim.x + threadIdx.x;
    if (i < E) {
        int d = __builtin_nontemporal_load(dst0 + i);
        int pos = atomicAdd(&cursor[d], 1);
        csr0[pos] = __builtin_nontemporal_load(src0 + i);
    } else if (i < 2 * E) {
        int e = i - E;
        int d = __builtin_nontemporal_load(dst1 + e);
        int pos = atomicAdd(&cursor[N + d], 1);
        csr1[pos * 2] = __builtin_nontemporal_load(src1 + e * 2);
        csr1[pos * 2 + 1] = __builtin_nontemporal_load(src1 + e * 2 + 1);
    } else if (i < 3 * E) {
        int e = i - 2 * E;
        int d = __builtin_nontemporal_load(dst2 + e);
        int pos = atomicAdd(&cursor[2 * N + d], 1);
        csr2[pos * 3] = __builtin_nontemporal_load(src2 + e * 3);
        csr2[pos * 3 + 1] = __builtin_nontemporal_load(src2 + e * 3 + 1);
        csr2[pos * 3 + 2] = __builtin_nontemporal_load(src2 + e * 3 + 2);
    }
}

// ---------------- per-node aggregation: one row per wave, lane owns 2 columns ----------------
// Round-5: BRANCH-FREE batched gathers. R3's per-ke `if` guards blocked load
// clustering (VGPR_Count=24 proved no batch was ever live), leaving ~1 gather
// in flight per wave -> pure latency bound. Now: CSR index is CLAMPED (not
// guarded), all CH_E*A gathers issue unconditionally back-to-back (clamped
// duplicates hit the same L1 line), and validity is applied as a select at
// accumulate time. No control flow between loads -> one vmcnt wait per chunk.
template <int A>
__device__ inline void agg_wave(const u16* __restrict__ xb, const int* __restrict__ csr,
                                int o0, int deg, int lane, u16* __restrict__ outp) {
    constexpr int CH_E = 8;       // edges per chunk
    constexpr int CH = CH_E * A;  // csr items per chunk (8/16/24)
    float acc[A][2];
#pragma unroll
    for (int s = 0; s < A; ++s) {
        acc[s][0] = 0.f;
        acc[s][1] = 0.f;
    }
    const int items = deg * A;
    const int base = o0 * A;
    const int last = base + items - 1;
    const unsigned* __restrict__ xw = (const unsigned*)xb;

    for (int e0 = 0; e0 < deg; e0 += CH_E) {
        int rv = 0;
        if (lane < CH) {
            int idx = base + e0 * A + lane;
            if (idx > last) idx = last;  // clamp, never guard: valid row id either way
            rv = csr[idx];
        }
        int erem = deg - e0;  // wave-uniform
        unsigned u[CH_E][A];
        // ---- issue ALL gathers for this chunk, unconditionally ----
#pragma unroll
        for (int ke = 0; ke < CH_E; ++ke)
#pragma unroll
            for (int s = 0; s < A; ++s) {
                int r = __builtin_amdgcn_readlane(rv, ke * A + s);  // SGPR row id
                u[ke][s] = xw[((size_t)(unsigned)r << 6) + lane];
            }
        // ---- predicated accumulate (clamped duplicates discarded) ----
#pragma unroll
        for (int ke = 0; ke < CH_E; ++ke) {
            bool ok = ke < erem;
#pragma unroll
            for (int s = 0; s < A; ++s) {
                acc[s][0] += ok ? bflo(u[ke][s]) : 0.f;
                acc[s][1] += ok ? bfhi(u[ke][s]) : 0.f;
            }
        }
    }

    float norm = (deg > 0) ? 1.0f / (float)deg : 0.0f;
#pragma unroll
    for (int s = 0; s < A; ++s) {
        unsigned o = packbf(acc[s][0] * norm, acc[s][1] * norm);
        ((unsigned*)(outp + s * D))[lane] = o;  // normal store: gemm re-reads AG
    }
}

__global__ __launch_bounds__(256) void aggregate_kernel(
    const u16* __restrict__ xb, const int* __restrict__ counts, const int* __restrict__ offs,
    const int* __restrict__ csr0, const int* __restrict__ csr1, const int* __restrict__ csr2,
    u16* __restrict__ AG, int n0, int M, int N) {
    int w = __builtin_amdgcn_readfirstlane(threadIdx.x >> 6);
    int gw = blockIdx.x * 4 + w;
    int lane = threadIdx.x & 63;
    if (gw >= 3 * M) return;
    int type = (gw >= 2 * M) ? 2 : (gw >= M) ? 1 : 0;
    int l = gw - type * M;
    int n = n0 + l;
    u16* outp = AG + (size_t)l * 768;
    if (type == 0) {
        int o0 = __builtin_amdgcn_readfirstlane(offs[n]);
        int dg = __builtin_amdgcn_readfirstlane(counts[n]);
        agg_wave<1>(xb, csr0, o0, dg, lane, outp);
    } else if (type == 1) {
        int o0 = __builtin_amdgcn_readfirstlane(offs[N + n]);
        int dg = __builtin_amdgcn_readfirstlane(counts[N + n]);
        agg_wave<2>(xb, csr1, o0, dg, lane, outp + 128);
    } else {
        int o0 = __builtin_amdgcn_readfirstlane(offs[2 * N + n]);
        int dg = __builtin_amdgcn_readfirstlane(counts[2 * N + n]);
        agg_wave<3>(xb, csr2, o0, dg, lane, outp + 384);
    }
}

// ---------------- fused final GEMM: out = [x | AG] @ [WC^T; WA*] + bC ----------------
// Round-5: B-fragments load DIRECTLY from Wp (224 KB, L2-resident; 4 waves
// share L1 so per-kstep 16 KB slab is an effective broadcast). Bs staging and
// its LDS traffic removed; LDS = As only (18.4 KB) -> more blocks/CU.
__global__ __launch_bounds__(256) void final_gemm_kernel(
    const u16* __restrict__ xb, const u16* __restrict__ AG, const u16* __restrict__ Wp,
    const float* __restrict__ bC, float* __restrict__ out, int n0, int M) {
    constexpr int KSTEPS = 14;  // 896 / 64
    alignas(16) __shared__ u16 As[128][72];

    const int tid = threadIdx.x;
    const int wave = tid >> 6;
    const int lane = tid & 63;
    const int m0 = blockIdx.x * 128;

    floatx4 acc[2][8];
#pragma unroll
    for (int s = 0; s < 2; ++s)
#pragma unroll
        for (int t = 0; t < 8; ++t) acc[s][t] = floatx4{0.f, 0.f, 0.f, 0.f};

    for (int ks = 0; ks < KSTEPS; ++ks) {
#pragma unroll
        for (int it = 0; it < 4; ++it) {
            int chunk = tid + it * 256;
            int row = chunk >> 3, part = chunk & 7;
            int e = m0 + row;
            const u16* srcp;
            if (ks < 2) {
                int g = (e < M) ? (n0 + e) : n0;
                srcp = xb + (size_t)g * D + ks * 64;
            } else {
                int l = (e < M) ? e : 0;
                srcp = AG + (size_t)l * 768 + (ks - 2) * 64;
            }
            *(uintx4*)(&As[row][part * 8]) = *(const uintx4*)(srcp + part * 8);
        }
        __syncthreads();
#pragma unroll
        for (int sub = 0; sub < 2; ++sub) {
            bf16x8 bfrag[8];
#pragma unroll
            for (int t = 0; t < 8; ++t)
                bfrag[t] = *(const bf16x8*)(Wp + (size_t)ks * 8192 +
                                            ((size_t)((sub * 8 + t) * 64 + lane)) * 8);
#pragma unroll
            for (int strip = 0; strip < 2; ++strip) {
                int row = wave * 32 + strip * 16 + (lane & 15);
                bf16x8 afrag = *(const bf16x8*)(&As[row][sub * 32 + ((lane >> 4) * 8)]);
#pragma unroll
                for (int t = 0; t < 8; ++t)
                    acc[strip][t] = __builtin_amdgcn_mfma_f32_16x16x32_bf16(
                        afrag, bfrag[t], acc[strip][t], 0, 0, 0);
            }
        }
        __syncthreads();
    }

#pragma unroll
    for (int strip = 0; strip < 2; ++strip) {
#pragma unroll
        for (int r = 0; r < 4; ++r) {
            int row = wave * 32 + strip * 16 + (lane >> 4) * 4 + r;
            int e = m0 + row;
            if (e >= M) continue;
            size_t base = (size_t)(n0 + e) * D;
#pragma unroll
            for (int t = 0; t < 8; ++t) {
                int col = 16 * t + (lane & 15);
                out[base + col] = acc[strip][t][r] + bC[col];
            }
        }
    }
}

extern "C" void kernel_launch(void* const* d_in, const int* in_sizes, int n_in,
                              void* d_out, int out_size, void* d_ws, size_t ws_size,
                              hipStream_t stream) {
    const float* x = (const float*)d_in[0];
    const int* src0 = (const int*)d_in[1];
    const int* dst0 = (const int*)d_in[2];
    const int* src1 = (const int*)d_in[3];
    const int* dst1 = (const int*)d_in[4];
    const int* src2 = (const int*)d_in[5];
    const int* dst2 = (const int*)d_in[6];
    const float* WA0 = (const float*)d_in[7];
    const float* WA1 = (const float*)d_in[8];
    const float* WA2 = (const float*)d_in[9];
    const float* WC = (const float*)d_in[10];
    const float* bC = (const float*)d_in[11];

    const int N = in_sizes[0] / D;  // 100000
    const int E = in_sizes[2];      // 500000

    auto align256 = [](size_t v) { return (v + 255) & ~(size_t)255; };
    char* ws = (char*)d_ws;
    size_t ofs = 0;
    u16* xb = (u16*)(ws + ofs);      ofs = align256(ofs + (size_t)N * D * sizeof(u16));
    int* counts = (int*)(ws + ofs);  ofs = align256(ofs + ((size_t)3 * N + 4) * sizeof(int));
    int* counters = counts + 3 * N;  // 3 ints, zeroed with counts
    int* offs = (int*)(ws + ofs);    ofs = align256(ofs + (size_t)3 * N * sizeof(int));
    int* cursor = (int*)(ws + ofs);  ofs = align256(ofs + (size_t)3 * N * sizeof(int));
    int* csr0 = (int*)(ws + ofs);    // E ints
    int* csr1 = csr0 + E;            // 2E ints
    int* csr2 = csr1 + 2 * E;        // 3E ints
    ofs = align256(ofs + (size_t)6 * E * sizeof(int));
    u16* Wp = (u16*)(ws + ofs);      ofs = align256(ofs + (size_t)896 * D * sizeof(u16));
    u16* AG = (u16*)(ws + ofs);

    size_t avail = (ws_size > ofs) ? (ws_size - ofs) : 0;
    long long ncMax = (long long)(avail / (768 * sizeof(u16)));
    int Nc = (int)((ncMax / 128) * 128);
    if (Nc > N) Nc = ((N + 127) / 128) * 128;
    if (Nc < 128) Nc = 128;

    // prep
    zero_int_kernel<<<512, 256, 0, stream>>>(counts, 3 * N + 4);

    int cb3 = (3 * E + 255) / 256;
    int packb = (14336 + 255) / 256;  // 56
    prep_kernel<<<CVB + cb3 + packb, 256, 0, stream>>>(x, xb, N * D / 4,
                                                       dst0, dst1, dst2, counts, E, N, cb3,
                                                       WC, WA0, WA1, WA2, Wp);

    int bpt = (N + 255) / 256;
    offs_kernel<<<3 * bpt, 256, 0, stream>>>(counts, offs, cursor, counters, N, bpt);

    scatter3_kernel<<<cb3, 256, 0, stream>>>(dst0, src0, dst1, src1, dst2, src2,
                                             cursor, csr0, csr1, csr2, E, N);

    for (int n0 = 0; n0 < N; n0 += Nc) {
        int M = (N - n0 < Nc) ? (N - n0) : Nc;
        int ab = (3 * M + 3) / 4;
        aggregate_kernel<<<ab, 256, 0, stream>>>(xb, counts, offs, csr0, csr1, csr2,
                                                 AG, n0, M, N);
        final_gemm_kernel<<<(M + 127) / 128, 256, 0, stream>>>(xb, AG, Wp, bC,
                                                               (float*)d_out, n0, M);
    }
}

// Round 6
// 501.507 us; speedup vs baseline: 6.0803x; 1.0151x over previous
//
#include <hip/hip_runtime.h>
#include <hip/hip_bf16.h>

typedef unsigned short u16;
typedef __bf16 bf16x8 __attribute__((ext_vector_type(8)));
typedef float floatx4 __attribute__((ext_vector_type(4)));
typedef unsigned uintx4 __attribute__((ext_vector_type(4)));
typedef unsigned short ushortx4 __attribute__((ext_vector_type(4)));

static constexpr int D = 128;

__device__ inline float bflo(unsigned u) { return __uint_as_float(u << 16); }
__device__ inline float bfhi(unsigned u) { return __uint_as_float(u & 0xffff0000u); }
__device__ inline unsigned packbf(float a, float b) {
    unsigned lo = __hip_bfloat16_raw(__float2bfloat16(a)).x;
    unsigned hi = __hip_bfloat16_raw(__float2bfloat16(b)).x;
    return lo | (hi << 16);
}

// ---------------- zero ints ----------------
__global__ void zero_int_kernel(int* __restrict__ p, int n) {
    int i = blockIdx.x * blockDim.x + threadIdx.x;
    int stride = gridDim.x * blockDim.x;
    for (; i < n; i += stride) p[i] = 0;
}

// ---------------- merged prep: convert x | count3 | pack weights ----------------
static constexpr int CVB = 1024;  // convert blocks

__global__ void prep_kernel(const float* __restrict__ x, u16* __restrict__ xb, int n4,
                            const int* __restrict__ dst0, const int* __restrict__ dst1,
                            const int* __restrict__ dst2, int* __restrict__ counts,
                            int E, int N, int cb3,
                            const float* __restrict__ WC, const float* __restrict__ WA0,
                            const float* __restrict__ WA1, const float* __restrict__ WA2,
                            u16* __restrict__ Wp) {
    int b = blockIdx.x;
    if (b < CVB) {
        int i = b * blockDim.x + threadIdx.x;
        int stride = CVB * blockDim.x;
        for (; i < n4; i += stride) {
            floatx4 v = __builtin_nontemporal_load((const floatx4*)x + i);
            ushortx4 o;
            o.x = __hip_bfloat16_raw(__float2bfloat16(v.x)).x;
            o.y = __hip_bfloat16_raw(__float2bfloat16(v.y)).x;
            o.z = __hip_bfloat16_raw(__float2bfloat16(v.z)).x;
            o.w = __hip_bfloat16_raw(__float2bfloat16(v.w)).x;
            *((ushortx4*)xb + i) = o;
        }
    } else if (b < CVB + cb3) {
        int i = (b - CVB) * blockDim.x + threadIdx.x;
        if (i < E) {
            atomicAdd(&counts[dst0[i]], 1);
        } else if (i < 2 * E) {
            atomicAdd(&counts[N + dst1[i - E]], 1);
        } else if (i < 3 * E) {
            atomicAdd(&counts[2 * N + dst2[i - 2 * E]], 1);
        }
    } else {
        // Wp (u16): [0,16384)=WC^T, [16384,32768)=WA0, [32768,65536)=WA1, [65536,114688)=WA2
        int c = (b - CVB - cb3) * blockDim.x + threadIdx.x;
        if (c >= 14336) return;
        const float* W;
        int K, transposed, cl;
        u16* out;
        if (c < 2048) {
            W = WC; K = 128; transposed = 1; cl = c; out = Wp;
        } else if (c < 4096) {
            W = WA0; K = 128; transposed = 0; cl = c - 2048; out = Wp + 16384;
        } else if (c < 8192) {
            W = WA1; K = 256; transposed = 0; cl = c - 4096; out = Wp + 32768;
        } else {
            W = WA2; K = 384; transposed = 0; cl = c - 8192; out = Wp + 65536;
        }
        int s = cl >> 9, rem = cl & 511, t = rem >> 6, l = rem & 63;
        int kbase = 32 * s + ((l >> 4) * 8);
        int n = 16 * t + (l & 15);
#pragma unroll
        for (int j = 0; j < 8; ++j) {
            int k = kbase + j;
            float w = transposed ? W[n * K + k] : W[k * D + n];
            out[(size_t)cl * 8 + j] = __hip_bfloat16_raw(__float2bfloat16(w)).x;
        }
    }
}

// ---------------- offsets: wave scan + one atomic per wave ----------------
__global__ __launch_bounds__(256) void offs_kernel(const int* __restrict__ counts,
                                                   int* __restrict__ offs,
                                                   int* __restrict__ cursor,
                                                   int* __restrict__ counters,
                                                   int N, int bpt) {
    int type = blockIdx.x / bpt;
    int n = (blockIdx.x - type * bpt) * 256 + threadIdx.x;
    int lane = threadIdx.x & 63;
    int i = type * N + n;
    int v = (n < N) ? counts[i] : 0;
    int incl = v;
#pragma unroll
    for (int d = 1; d < 64; d <<= 1) {
        int t = __shfl_up(incl, d, 64);
        if (lane >= d) incl += t;
    }
    int total = __shfl(incl, 63, 64);
    int base = 0;
    if (lane == 63) base = atomicAdd(&counters[type], total);
    base = __shfl(base, 63, 64);
    int off = base + incl - v;
    if (n < N) {
        offs[i] = off;
        cursor[i] = off;
    }
}

// ---------------- CSR scatter (all three edge types, one launch) ----------------
// csr2 PADDED to stride 4: one aligned 16B store instead of 3 scattered dwords
// (halves the random-line touches of the biggest edge type). Pad slot = 0
// (valid row id; aggregate's clamped lanes may read it, value discarded).
__global__ void scatter3_kernel(const int* __restrict__ dst0, const int* __restrict__ src0,
                                const int* __restrict__ dst1, const int* __restrict__ src1,
                                const int* __restrict__ dst2, const int* __restrict__ src2,
                                int* __restrict__ cursor,
                                int* __restrict__ csr0, int* __restrict__ csr1,
                                int* __restrict__ csr2, int E, int N) {
    int i = blockIdx.x * blockDim.x + threadIdx.x;
    if (i < E) {
        int d = __builtin_nontemporal_load(dst0 + i);
        int pos = atomicAdd(&cursor[d], 1);
        csr0[pos] = __builtin_nontemporal_load(src0 + i);
    } else if (i < 2 * E) {
        int e = i - E;
        int d = __builtin_nontemporal_load(dst1 + e);
        int pos = atomicAdd(&cursor[N + d], 1);
        csr1[pos * 2] = __builtin_nontemporal_load(src1 + e * 2);
        csr1[pos * 2 + 1] = __builtin_nontemporal_load(src1 + e * 2 + 1);
    } else if (i < 3 * E) {
        int e = i - 2 * E;
        int d = __builtin_nontemporal_load(dst2 + e);
        int pos = atomicAdd(&cursor[2 * N + d], 1);
        int a = __builtin_nontemporal_load(src2 + e * 3);
        int b = __builtin_nontemporal_load(src2 + e * 3 + 1);
        int c = __builtin_nontemporal_load(src2 + e * 3 + 2);
        int4 o; o.x = a; o.y = b; o.z = c; o.w = 0;
        *(int4*)(csr2 + (size_t)pos * 4) = o;
    }
}

// ---------------- per-node aggregation: one row per wave, lane owns 2 columns ----------------
// Round-6: full chunks (wave-uniform branch) accumulate with NO selects;
// tail chunks zero the loaded dword with ONE cndmask instead of two float
// selects. Loads stay branch-free/clamped (the R5 batching win).
template <int A>
__device__ inline void agg_wave(const u16* __restrict__ xb, const int* __restrict__ csr,
                                int o0, int deg, int lane, u16* __restrict__ outp) {
    constexpr int ST = (A == 3) ? 4 : A;  // csr stride per edge (csr2 padded)
    constexpr int CH_E = 8;               // edges per chunk
    constexpr int CH = CH_E * ST;         // csr items per chunk (8/16/32)
    float acc[A][2];
#pragma unroll
    for (int s = 0; s < A; ++s) {
        acc[s][0] = 0.f;
        acc[s][1] = 0.f;
    }
    const int base = o0 * ST;
    const int last = base + deg * ST - 1;
    const unsigned* __restrict__ xw = (const unsigned*)xb;

    for (int e0 = 0; e0 < deg; e0 += CH_E) {
        int rv = 0;
        if (lane < CH) {
            int idx = base + e0 * ST + lane;
            if (idx > last) idx = last;  // clamp, never guard
            rv = csr[idx];
        }
        int erem = deg - e0;  // wave-uniform
        unsigned u[CH_E][A];
        // ---- issue ALL gathers for this chunk, unconditionally ----
#pragma unroll
        for (int ke = 0; ke < CH_E; ++ke)
#pragma unroll
            for (int s = 0; s < A; ++s) {
                int r = __builtin_amdgcn_readlane(rv, ke * ST + s);  // SGPR row id
                u[ke][s] = xw[((size_t)(unsigned)r << 6) + lane];
            }
        if (erem >= CH_E) {
            // ---- full chunk: no predication at all ----
#pragma unroll
            for (int ke = 0; ke < CH_E; ++ke)
#pragma unroll
                for (int s = 0; s < A; ++s) {
                    acc[s][0] += bflo(u[ke][s]);
                    acc[s][1] += bfhi(u[ke][s]);
                }
        } else {
            // ---- tail: one cndmask per dword (zeroed dword adds 0.f twice) ----
#pragma unroll
            for (int ke = 0; ke < CH_E; ++ke) {
                bool ok = ke < erem;
#pragma unroll
                for (int s = 0; s < A; ++s) {
                    unsigned uz = ok ? u[ke][s] : 0u;
                    acc[s][0] += bflo(uz);
                    acc[s][1] += bfhi(uz);
                }
            }
        }
    }

    float norm = (deg > 0) ? 1.0f / (float)deg : 0.0f;
#pragma unroll
    for (int s = 0; s < A; ++s) {
        unsigned o = packbf(acc[s][0] * norm, acc[s][1] * norm);
        ((unsigned*)(outp + s * D))[lane] = o;  // normal store: gemm re-reads AG
    }
}

__global__ __launch_bounds__(256) void aggregate_kernel(
    const u16* __restrict__ xb, const int* __restrict__ counts, const int* __restrict__ offs,
    const int* __restrict__ csr0, const int* __restrict__ csr1, const int* __restrict__ csr2,
    u16* __restrict__ AG, int n0, int M, int N) {
    int w = __builtin_amdgcn_readfirstlane(threadIdx.x >> 6);
    int gw = blockIdx.x * 4 + w;
    int lane = threadIdx.x & 63;
    if (gw >= 3 * M) return;
    int type = (gw >= 2 * M) ? 2 : (gw >= M) ? 1 : 0;
    int l = gw - type * M;
    int n = n0 + l;
    u16* outp = AG + (size_t)l * 768;
    if (type == 0) {
        int o0 = __builtin_amdgcn_readfirstlane(offs[n]);
        int dg = __builtin_amdgcn_readfirstlane(counts[n]);
        agg_wave<1>(xb, csr0, o0, dg, lane, outp);
    } else if (type == 1) {
        int o0 = __builtin_amdgcn_readfirstlane(offs[N + n]);
        int dg = __builtin_amdgcn_readfirstlane(counts[N + n]);
        agg_wave<2>(xb, csr1, o0, dg, lane, outp + 128);
    } else {
        int o0 = __builtin_amdgcn_readfirstlane(offs[2 * N + n]);
        int dg = __builtin_amdgcn_readfirstlane(counts[2 * N + n]);
        agg_wave<3>(xb, csr2, o0, dg, lane, outp + 384);
    }
}

// ---------------- fused final GEMM: out = [x | AG] @ [WC^T; WA*] + bC ----------------
// Round-6: register double-buffered A-staging. Old loop serialized
// {global load -> vmcnt(0) drain at barrier -> MFMA} per kstep (~800cy latency
// vs ~160cy compute). Now kstep+1's 4x uint4 are fetched during MFMA(kstep),
// so the global latency hides under compute + the following barrier.
__global__ __launch_bounds__(256) void final_gemm_kernel(
    const u16* __restrict__ xb, const u16* __restrict__ AG, const u16* __restrict__ Wp,
    const float* __restrict__ bC, float* __restrict__ out, int n0, int M) {
    constexpr int KSTEPS = 14;  // 896 / 64
    alignas(16) __shared__ u16 As[128][72];

    const int tid = threadIdx.x;
    const int wave = tid >> 6;
    const int lane = tid & 63;
    const int m0 = blockIdx.x * 128;

    floatx4 acc[2][8];
#pragma unroll
    for (int s = 0; s < 2; ++s)
#pragma unroll
        for (int t = 0; t < 8; ++t) acc[s][t] = floatx4{0.f, 0.f, 0.f, 0.f};

    auto ld = [&](int ks, int it) -> uintx4 {
        int chunk = tid + it * 256;
        int row = chunk >> 3, part = chunk & 7;
        int e = m0 + row;
        const u16* srcp;
        if (ks < 2) {
            int g = (e < M) ? (n0 + e) : n0;
            srcp = xb + (size_t)g * D + ks * 64;
        } else {
            int l = (e < M) ? e : 0;
            srcp = AG + (size_t)l * 768 + (ks - 2) * 64;
        }
        return *(const uintx4*)(srcp + part * 8);
    };

    uintx4 st[4];
#pragma unroll
    for (int it = 0; it < 4; ++it) st[it] = ld(0, it);

    for (int ks = 0; ks < KSTEPS; ++ks) {
#pragma unroll
        for (int it = 0; it < 4; ++it) {
            int chunk = tid + it * 256;
            int row = chunk >> 3, part = chunk & 7;
            *(uintx4*)(&As[row][part * 8]) = st[it];
        }
        __syncthreads();
        if (ks < KSTEPS - 1) {
#pragma unroll
            for (int it = 0; it < 4; ++it) st[it] = ld(ks + 1, it);
        }
#pragma unroll
        for (int sub = 0; sub < 2; ++sub) {
            bf16x8 bfrag[8];
#pragma unroll
            for (int t = 0; t < 8; ++t)
                bfrag[t] = *(const bf16x8*)(Wp + (size_t)ks * 8192 +
                                            ((size_t)((sub * 8 + t) * 64 + lane)) * 8);
#pragma unroll
            for (int strip = 0; strip < 2; ++strip) {
                int row = wave * 32 + strip * 16 + (lane & 15);
                bf16x8 afrag = *(const bf16x8*)(&As[row][sub * 32 + ((lane >> 4) * 8)]);
#pragma unroll
                for (int t = 0; t < 8; ++t)
                    acc[strip][t] = __builtin_amdgcn_mfma_f32_16x16x32_bf16(
                        afrag, bfrag[t], acc[strip][t], 0, 0, 0);
            }
        }
        __syncthreads();
    }

#pragma unroll
    for (int strip = 0; strip < 2; ++strip) {
#pragma unroll
        for (int r = 0; r < 4; ++r) {
            int row = wave * 32 + strip * 16 + (lane >> 4) * 4 + r;
            int e = m0 + row;
            if (e >= M) continue;
            size_t base = (size_t)(n0 + e) * D;
#pragma unroll
            for (int t = 0; t < 8; ++t) {
                int col = 16 * t + (lane & 15);
                out[base + col] = acc[strip][t][r] + bC[col];
            }
        }
    }
}

extern "C" void kernel_launch(void* const* d_in, const int* in_sizes, int n_in,
                              void* d_out, int out_size, void* d_ws, size_t ws_size,
                              hipStream_t stream) {
    const float* x = (const float*)d_in[0];
    const int* src0 = (const int*)d_in[1];
    const int* dst0 = (const int*)d_in[2];
    const int* src1 = (const int*)d_in[3];
    const int* dst1 = (const int*)d_in[4];
    const int* src2 = (const int*)d_in[5];
    const int* dst2 = (const int*)d_in[6];
    const float* WA0 = (const float*)d_in[7];
    const float* WA1 = (const float*)d_in[8];
    const float* WA2 = (const float*)d_in[9];
    const float* WC = (const float*)d_in[10];
    const float* bC = (const float*)d_in[11];

    const int N = in_sizes[0] / D;  // 100000
    const int E = in_sizes[2];      // 500000

    auto align256 = [](size_t v) { return (v + 255) & ~(size_t)255; };
    char* ws = (char*)d_ws;
    size_t ofs = 0;
    u16* xb = (u16*)(ws + ofs);      ofs = align256(ofs + (size_t)N * D * sizeof(u16));
    int* counts = (int*)(ws + ofs);  ofs = align256(ofs + ((size_t)3 * N + 4) * sizeof(int));
    int* counters = counts + 3 * N;  // 3 ints, zeroed with counts
    int* offs = (int*)(ws + ofs);    ofs = align256(ofs + (size_t)3 * N * sizeof(int));
    int* cursor = (int*)(ws + ofs);  ofs = align256(ofs + (size_t)3 * N * sizeof(int));
    int* csr0 = (int*)(ws + ofs);    // E ints
    int* csr1 = csr0 + E;            // 2E ints
    int* csr2 = csr1 + 2 * E;        // 4E ints (stride-4 padded)
    ofs = align256(ofs + (size_t)7 * E * sizeof(int));
    u16* Wp = (u16*)(ws + ofs);      ofs = align256(ofs + (size_t)896 * D * sizeof(u16));
    u16* AG = (u16*)(ws + ofs);

    size_t avail = (ws_size > ofs) ? (ws_size - ofs) : 0;
    long long ncMax = (long long)(avail / (768 * sizeof(u16)));
    int Nc = (int)((ncMax / 128) * 128);
    if (Nc > N) Nc = ((N + 127) / 128) * 128;
    if (Nc < 128) Nc = 128;

    // prep
    zero_int_kernel<<<512, 256, 0, stream>>>(counts, 3 * N + 4);

    int cb3 = (3 * E + 255) / 256;
    int packb = (14336 + 255) / 256;  // 56
    prep_kernel<<<CVB + cb3 + packb, 256, 0, stream>>>(x, xb, N * D / 4,
                                                       dst0, dst1, dst2, counts, E, N, cb3,
                                                       WC, WA0, WA1, WA2, Wp);

    int bpt = (N + 255) / 256;
    offs_kernel<<<3 * bpt, 256, 0, stream>>>(counts, offs, cursor, counters, N, bpt);

    scatter3_kernel<<<cb3, 256, 0, stream>>>(dst0, src0, dst1, src1, dst2, src2,
                                             cursor, csr0, csr1, csr2, E, N);

    for (int n0 = 0; n0 < N; n0 += Nc) {
        int M = (N - n0 < Nc) ? (N - n0) : Nc;
        int ab = (3 * M + 3) / 4;
        aggregate_kernel<<<ab, 256, 0, stream>>>(xb, counts, offs, csr0, csr1, csr2,
                                                 AG, n0, M, N);
        final_gemm_kernel<<<(M + 127) / 128, 256, 0, stream>>>(xb, AG, Wp, bC,
                                                               (float*)d_out, n0, M);
    }
}

// Round 7
// 489.115 us; speedup vs baseline: 6.2343x; 1.0253x over previous
//
#include <hip/hip_runtime.h>
#include <hip/hip_bf16.h>

typedef unsigned short u16;
typedef __bf16 bf16x8 __attribute__((ext_vector_type(8)));
typedef float floatx4 __attribute__((ext_vector_type(4)));
typedef float floatx2 __attribute__((ext_vector_type(2)));
typedef unsigned uintx4 __attribute__((ext_vector_type(4)));
typedef unsigned short ushortx4 __attribute__((ext_vector_type(4)));

static constexpr int D = 128;

__device__ inline float bflo(unsigned u) { return __uint_as_float(u << 16); }
__device__ inline float bfhi(unsigned u) { return __uint_as_float(u & 0xffff0000u); }
__device__ inline unsigned packbf(float a, float b) {
    unsigned lo = __hip_bfloat16_raw(__float2bfloat16(a)).x;
    unsigned hi = __hip_bfloat16_raw(__float2bfloat16(b)).x;
    return lo | (hi << 16);
}

// ---------------- zero ints ----------------
__global__ void zero_int_kernel(int* __restrict__ p, int n) {
    int i = blockIdx.x * blockDim.x + threadIdx.x;
    int stride = gridDim.x * blockDim.x;
    for (; i < n; i += stride) p[i] = 0;
}

// ---------------- merged prep: convert x | count3 | pack weights ----------------
static constexpr int CVB = 1024;  // convert blocks

__global__ void prep_kernel(const float* __restrict__ x, u16* __restrict__ xb, int n4,
                            const int* __restrict__ dst0, const int* __restrict__ dst1,
                            const int* __restrict__ dst2, int* __restrict__ counts,
                            int E, int N, int cb3,
                            const float* __restrict__ WC, const float* __restrict__ WA0,
                            const float* __restrict__ WA1, const float* __restrict__ WA2,
                            u16* __restrict__ Wp) {
    int b = blockIdx.x;
    if (b < CVB) {
        int i = b * blockDim.x + threadIdx.x;
        int stride = CVB * blockDim.x;
        for (; i < n4; i += stride) {
            floatx4 v = __builtin_nontemporal_load((const floatx4*)x + i);
            ushortx4 o;
            o.x = __hip_bfloat16_raw(__float2bfloat16(v.x)).x;
            o.y = __hip_bfloat16_raw(__float2bfloat16(v.y)).x;
            o.z = __hip_bfloat16_raw(__float2bfloat16(v.z)).x;
            o.w = __hip_bfloat16_raw(__float2bfloat16(v.w)).x;
            *((ushortx4*)xb + i) = o;
        }
    } else if (b < CVB + cb3) {
        int i = (b - CVB) * blockDim.x + threadIdx.x;
        if (i < E) {
            atomicAdd(&counts[dst0[i]], 1);
        } else if (i < 2 * E) {
            atomicAdd(&counts[N + dst1[i - E]], 1);
        } else if (i < 3 * E) {
            atomicAdd(&counts[2 * N + dst2[i - 2 * E]], 1);
        }
    } else {
        // Wp (u16): [0,16384)=WC^T, [16384,32768)=WA0, [32768,65536)=WA1, [65536,114688)=WA2
        int c = (b - CVB - cb3) * blockDim.x + threadIdx.x;
        if (c >= 14336) return;
        const float* W;
        int K, transposed, cl;
        u16* out;
        if (c < 2048) {
            W = WC; K = 128; transposed = 1; cl = c; out = Wp;
        } else if (c < 4096) {
            W = WA0; K = 128; transposed = 0; cl = c - 2048; out = Wp + 16384;
        } else if (c < 8192) {
            W = WA1; K = 256; transposed = 0; cl = c - 4096; out = Wp + 32768;
        } else {
            W = WA2; K = 384; transposed = 0; cl = c - 8192; out = Wp + 65536;
        }
        int s = cl >> 9, rem = cl & 511, t = rem >> 6, l = rem & 63;
        int kbase = 32 * s + ((l >> 4) * 8);
        int n = 16 * t + (l & 15);
#pragma unroll
        for (int j = 0; j < 8; ++j) {
            int k = kbase + j;
            float w = transposed ? W[n * K + k] : W[k * D + n];
            out[(size_t)cl * 8 + j] = __hip_bfloat16_raw(__float2bfloat16(w)).x;
        }
    }
}

// ---------------- offsets: wave scan + one atomic per wave ----------------
__global__ __launch_bounds__(256) void offs_kernel(const int* __restrict__ counts,
                                                   int* __restrict__ offs,
                                                   int* __restrict__ cursor,
                                                   int* __restrict__ counters,
                                                   int N, int bpt) {
    int type = blockIdx.x / bpt;
    int n = (blockIdx.x - type * bpt) * 256 + threadIdx.x;
    int lane = threadIdx.x & 63;
    int i = type * N + n;
    int v = (n < N) ? counts[i] : 0;
    int incl = v;
#pragma unroll
    for (int d = 1; d < 64; d <<= 1) {
        int t = __shfl_up(incl, d, 64);
        if (lane >= d) incl += t;
    }
    int total = __shfl(incl, 63, 64);
    int base = 0;
    if (lane == 63) base = atomicAdd(&counters[type], total);
    base = __shfl(base, 63, 64);
    int off = base + incl - v;
    if (n < N) {
        offs[i] = off;
        cursor[i] = off;
    }
}

// ---------------- CSR scatter (all three edge types, one launch) ----------------
// csr2 PADDED to stride 4: one aligned 16B store; pad slot = 0 (valid row id,
// value discarded by aggregate's tail predication).
__global__ void scatter3_kernel(const int* __restrict__ dst0, const int* __restrict__ src0,
                                const int* __restrict__ dst1, const int* __restrict__ src1,
                                const int* __restrict__ dst2, const int* __restrict__ src2,
                                int* __restrict__ cursor,
                                int* __restrict__ csr0, int* __restrict__ csr1,
                                int* __restrict__ csr2, int E, int N) {
    int i = blockIdx.x * blockDim.x + threadIdx.x;
    if (i < E) {
        int d = __builtin_nontemporal_load(dst0 + i);
        int pos = atomicAdd(&cursor[d], 1);
        csr0[pos] = __builtin_nontemporal_load(src0 + i);
    } else if (i < 2 * E) {
        int e = i - E;
        int d = __builtin_nontemporal_load(dst1 + e);
        int pos = atomicAdd(&cursor[N + d], 1);
        csr1[pos * 2] = __builtin_nontemporal_load(src1 + e * 2);
        csr1[pos * 2 + 1] = __builtin_nontemporal_load(src1 + e * 2 + 1);
    } else if (i < 3 * E) {
        int e = i - 2 * E;
        int d = __builtin_nontemporal_load(dst2 + e);
        int pos = atomicAdd(&cursor[2 * N + d], 1);
        int a = __builtin_nontemporal_load(src2 + e * 3);
        int b = __builtin_nontemporal_load(src2 + e * 3 + 1);
        int c = __builtin_nontemporal_load(src2 + e * 3 + 2);
        int4 o; o.x = a; o.y = b; o.z = c; o.w = 0;
        *(int4*)(csr2 + (size_t)pos * 4) = o;
    }
}

// ---------------- per-node aggregation: one row per wave, lane owns 2 columns ----------------
// Round-7: deeper load batches (CH_E 12/10/8 -> 12/20/24 loads in flight) to
// probe whether ~4.2 TB/s fabric is a ceiling or a concurrency shortfall, and
// floatx2 accumulators (pk_add-friendly: 3 VALU per gathered dword).
template <int A>
__device__ inline void agg_wave(const u16* __restrict__ xb, const int* __restrict__ csr,
                                int o0, int deg, int lane, u16* __restrict__ outp) {
    constexpr int ST = (A == 3) ? 4 : A;  // csr stride per edge (csr2 padded)
    constexpr int CH_E = (A == 1) ? 12 : (A == 2) ? 10 : 8;  // edges per chunk
    constexpr int CH = CH_E * ST;         // csr items per chunk (12/20/32)
    floatx2 acc[A];
#pragma unroll
    for (int s = 0; s < A; ++s) acc[s] = floatx2{0.f, 0.f};
    const int base = o0 * ST;
    const int last = base + deg * ST - 1;
    const unsigned* __restrict__ xw = (const unsigned*)xb;

    for (int e0 = 0; e0 < deg; e0 += CH_E) {
        int rv = 0;
        if (lane < CH) {
            int idx = base + e0 * ST + lane;
            if (idx > last) idx = last;  // clamp, never guard
            rv = csr[idx];
        }
        int erem = deg - e0;  // wave-uniform
        unsigned u[CH_E][A];
        // ---- issue ALL gathers for this chunk, unconditionally ----
#pragma unroll
        for (int ke = 0; ke < CH_E; ++ke)
#pragma unroll
            for (int s = 0; s < A; ++s) {
                int r = __builtin_amdgcn_readlane(rv, ke * ST + s);  // SGPR row id
                u[ke][s] = xw[((size_t)(unsigned)r << 6) + lane];
            }
        if (erem >= CH_E) {
            // ---- full chunk: no predication ----
#pragma unroll
            for (int ke = 0; ke < CH_E; ++ke)
#pragma unroll
                for (int s = 0; s < A; ++s) {
                    floatx2 f = {bflo(u[ke][s]), bfhi(u[ke][s])};
                    acc[s] += f;
                }
        } else {
            // ---- tail: one cndmask per dword ----
#pragma unroll
            for (int ke = 0; ke < CH_E; ++ke) {
                bool ok = ke < erem;
#pragma unroll
                for (int s = 0; s < A; ++s) {
                    unsigned uz = ok ? u[ke][s] : 0u;
                    floatx2 f = {bflo(uz), bfhi(uz)};
                    acc[s] += f;
                }
            }
        }
    }

    float norm = (deg > 0) ? 1.0f / (float)deg : 0.0f;
#pragma unroll
    for (int s = 0; s < A; ++s) {
        unsigned o = packbf(acc[s].x * norm, acc[s].y * norm);
        ((unsigned*)(outp + s * D))[lane] = o;  // normal store: gemm re-reads AG
    }
}

__global__ __launch_bounds__(256) void aggregate_kernel(
    const u16* __restrict__ xb, const int* __restrict__ counts, const int* __restrict__ offs,
    const int* __restrict__ csr0, const int* __restrict__ csr1, const int* __restrict__ csr2,
    u16* __restrict__ AG, int n0, int M, int N) {
    int w = __builtin_amdgcn_readfirstlane(threadIdx.x >> 6);
    int gw = blockIdx.x * 4 + w;
    int lane = threadIdx.x & 63;
    if (gw >= 3 * M) return;
    int type = (gw >= 2 * M) ? 2 : (gw >= M) ? 1 : 0;
    int l = gw - type * M;
    int n = n0 + l;
    u16* outp = AG + (size_t)l * 768;
    if (type == 0) {
        int o0 = __builtin_amdgcn_readfirstlane(offs[n]);
        int dg = __builtin_amdgcn_readfirstlane(counts[n]);
        agg_wave<1>(xb, csr0, o0, dg, lane, outp);
    } else if (type == 1) {
        int o0 = __builtin_amdgcn_readfirstlane(offs[N + n]);
        int dg = __builtin_amdgcn_readfirstlane(counts[N + n]);
        agg_wave<2>(xb, csr1, o0, dg, lane, outp + 128);
    } else {
        int o0 = __builtin_amdgcn_readfirstlane(offs[2 * N + n]);
        int dg = __builtin_amdgcn_readfirstlane(counts[2 * N + n]);
        agg_wave<3>(xb, csr2, o0, dg, lane, outp + 384);
    }
}

// ---------------- fused final GEMM: out = [x | AG] @ [WC^T; WA*] + bC ----------------
// Round-7: LDS double-buffer + ONE barrier per kstep (write buf^1 while other
// waves mfma buf is race-free across buffers; reads of buf complete before
// each wave's next-iter writes by program order + lgkm waits). Combined with
// R6's register prefetch, the global latency now spans a full kstep.
__global__ __launch_bounds__(256) void final_gemm_kernel(
    const u16* __restrict__ xb, const u16* __restrict__ AG, const u16* __restrict__ Wp,
    const float* __restrict__ bC, float* __restrict__ out, int n0, int M) {
    constexpr int KSTEPS = 14;  // 896 / 64
    alignas(16) __shared__ u16 As[2][128][72];

    const int tid = threadIdx.x;
    const int wave = tid >> 6;
    const int lane = tid & 63;
    const int m0 = blockIdx.x * 128;

    floatx4 acc[2][8];
#pragma unroll
    for (int s = 0; s < 2; ++s)
#pragma unroll
        for (int t = 0; t < 8; ++t) acc[s][t] = floatx4{0.f, 0.f, 0.f, 0.f};

    auto ld = [&](int ks, int it) -> uintx4 {
        int chunk = tid + it * 256;
        int row = chunk >> 3, part = chunk & 7;
        int e = m0 + row;
        const u16* srcp;
        if (ks < 2) {
            int g = (e < M) ? (n0 + e) : n0;
            srcp = xb + (size_t)g * D + ks * 64;
        } else {
            int l = (e < M) ? e : 0;
            srcp = AG + (size_t)l * 768 + (ks - 2) * 64;
        }
        return *(const uintx4*)(srcp + part * 8);
    };

    uintx4 st[4];
#pragma unroll
    for (int it = 0; it < 4; ++it) st[it] = ld(0, it);

    for (int ks = 0; ks < KSTEPS; ++ks) {
        const int cur = ks & 1;
#pragma unroll
        for (int it = 0; it < 4; ++it) {
            int chunk = tid + it * 256;
            int row = chunk >> 3, part = chunk & 7;
            *(uintx4*)(&As[cur][row][part * 8]) = st[it];
        }
        if (ks < KSTEPS - 1) {
#pragma unroll
            for (int it = 0; it < 4; ++it) st[it] = ld(ks + 1, it);
        }
        __syncthreads();
#pragma unroll
        for (int sub = 0; sub < 2; ++sub) {
            bf16x8 bfrag[8];
#pragma unroll
            for (int t = 0; t < 8; ++t)
                bfrag[t] = *(const bf16x8*)(Wp + (size_t)ks * 8192 +
                                            ((size_t)((sub * 8 + t) * 64 + lane)) * 8);
#pragma unroll
            for (int strip = 0; strip < 2; ++strip) {
                int row = wave * 32 + strip * 16 + (lane & 15);
                bf16x8 afrag = *(const bf16x8*)(&As[cur][row][sub * 32 + ((lane >> 4) * 8)]);
#pragma unroll
                for (int t = 0; t < 8; ++t)
                    acc[strip][t] = __builtin_amdgcn_mfma_f32_16x16x32_bf16(
                        afrag, bfrag[t], acc[strip][t], 0, 0, 0);
            }
        }
    }

#pragma unroll
    for (int strip = 0; strip < 2; ++strip) {
#pragma unroll
        for (int r = 0; r < 4; ++r) {
            int row = wave * 32 + strip * 16 + (lane >> 4) * 4 + r;
            int e = m0 + row;
            if (e >= M) continue;
            size_t base = (size_t)(n0 + e) * D;
#pragma unroll
            for (int t = 0; t < 8; ++t) {
                int col = 16 * t + (lane & 15);
                out[base + col] = acc[strip][t][r] + bC[col];
            }
        }
    }
}

extern "C" void kernel_launch(void* const* d_in, const int* in_sizes, int n_in,
                              void* d_out, int out_size, void* d_ws, size_t ws_size,
                              hipStream_t stream) {
    const float* x = (const float*)d_in[0];
    const int* src0 = (const int*)d_in[1];
    const int* dst0 = (const int*)d_in[2];
    const int* src1 = (const int*)d_in[3];
    const int* dst1 = (const int*)d_in[4];
    const int* src2 = (const int*)d_in[5];
    const int* dst2 = (const int*)d_in[6];
    const float* WA0 = (const float*)d_in[7];
    const float* WA1 = (const float*)d_in[8];
    const float* WA2 = (const float*)d_in[9];
    const float* WC = (const float*)d_in[10];
    const float* bC = (const float*)d_in[11];

    const int N = in_sizes[0] / D;  // 100000
    const int E = in_sizes[2];      // 500000

    auto align256 = [](size_t v) { return (v + 255) & ~(size_t)255; };
    char* ws = (char*)d_ws;
    size_t ofs = 0;
    u16* xb = (u16*)(ws + ofs);      ofs = align256(ofs + (size_t)N * D * sizeof(u16));
    int* counts = (int*)(ws + ofs);  ofs = align256(ofs + ((size_t)3 * N + 4) * sizeof(int));
    int* counters = counts + 3 * N;  // 3 ints, zeroed with counts
    int* offs = (int*)(ws + ofs);    ofs = align256(ofs + (size_t)3 * N * sizeof(int));
    int* cursor = (int*)(ws + ofs);  ofs = align256(ofs + (size_t)3 * N * sizeof(int));
    int* csr0 = (int*)(ws + ofs);    // E ints
    int* csr1 = csr0 + E;            // 2E ints
    int* csr2 = csr1 + 2 * E;        // 4E ints (stride-4 padded)
    ofs = align256(ofs + (size_t)7 * E * sizeof(int));
    u16* Wp = (u16*)(ws + ofs);      ofs = align256(ofs + (size_t)896 * D * sizeof(u16));
    u16* AG = (u16*)(ws + ofs);

    size_t avail = (ws_size > ofs) ? (ws_size - ofs) : 0;
    long long ncMax = (long long)(avail / (768 * sizeof(u16)));
    int Nc = (int)((ncMax / 128) * 128);
    if (Nc > N) Nc = ((N + 127) / 128) * 128;
    if (Nc < 128) Nc = 128;

    // prep
    zero_int_kernel<<<512, 256, 0, stream>>>(counts, 3 * N + 4);

    int cb3 = (3 * E + 255) / 256;
    int packb = (14336 + 255) / 256;  // 56
    prep_kernel<<<CVB + cb3 + packb, 256, 0, stream>>>(x, xb, N * D / 4,
                                                       dst0, dst1, dst2, counts, E, N, cb3,
                                                       WC, WA0, WA1, WA2, Wp);

    int bpt = (N + 255) / 256;
    offs_kernel<<<3 * bpt, 256, 0, stream>>>(counts, offs, cursor, counters, N, bpt);

    scatter3_kernel<<<cb3, 256, 0, stream>>>(dst0, src0, dst1, src1, dst2, src2,
                                             cursor, csr0, csr1, csr2, E, N);

    for (int n0 = 0; n0 < N; n0 += Nc) {
        int M = (N - n0 < Nc) ? (N - n0) : Nc;
        int ab = (3 * M + 3) / 4;
        aggregate_kernel<<<ab, 256, 0, stream>>>(xb, counts, offs, csr0, csr1, csr2,
                                                 AG, n0, M, N);
        final_gemm_kernel<<<(M + 127) / 128, 256, 0, stream>>>(xb, AG, Wp, bC,
                                                               (float*)d_out, n0, M);
    }
}